// Round 11
// baseline (111.381 us; speedup 1.0000x reference)
//
#include <hip/hip_runtime.h>
#include <hip/hip_bf16.h>
#include <math.h>

#define NS   16383
#define LPB  32
#define NBLK 512
#define TPB  512

// ---- ws byte layout ----
// [0..3] ticket u32 | [4..7] done u32 | [8..11] accz f32 | [12..15] acct f32
// [64 ..] st: u64[NBLK*64]  (per chunk x dim packed {tag,f32}; tag 0=empty 1=agg 2=incl)
#define WSB_ST 64
#define WS_ZERO_BYTES (64 + (size_t)NBLK * 64 * 8)

using bf16x8 = __attribute__((ext_vector_type(8))) short;
using f32x4  = __attribute__((ext_vector_type(4))) float;

__device__ __forceinline__ unsigned short f2bf(float f) {
    unsigned int x = __float_as_uint(f);
    return (unsigned short)((x + 0x7fffu + ((x >> 16) & 1u)) >> 16);
}
__device__ __forceinline__ float bf2f(unsigned short u) {
    return __uint_as_float(((unsigned int)u) << 16);
}
__device__ __forceinline__ float lrelu(float x) { return fmaxf(x, 0.01f * x); }

// A-fragment from swizzled LDS rows: row-major, short-idx ^= (row&7)<<3
__device__ __forceinline__ bf16x8 ldA(const unsigned short* buf, int strideSh, int row, int kc) {
    const int idx = (row * strideSh + kc) ^ ((row & 7) << 3);
    return *(const bf16x8*)(buf + idx);
}
// B-fragment: DIRECT load from row-major W [Nmax][Kst], bf16-convert in regs
__device__ __forceinline__ bf16x8 loadW(const float* __restrict__ W, const int Kst,
                                        const int klim, const int Nmax,
                                        const int n, const int kbase) {
    const bool nv = (n < Nmax);
    const int nc = nv ? n : (Nmax - 1);
    const float* p = W + (size_t)nc * Kst + kbase;
    float f[8];
    if (kbase + 7 < klim) {
        if ((Kst & 3) == 0) {
            const float4 a = *(const float4*)p;
            const float4 b = *(const float4*)(p + 4);
            f[0]=a.x; f[1]=a.y; f[2]=a.z; f[3]=a.w;
            f[4]=b.x; f[5]=b.y; f[6]=b.z; f[7]=b.w;
        } else {
            #pragma unroll
            for (int q = 0; q < 4; ++q) {
                const float2 t2 = *(const float2*)(p + 2 * q);
                f[2*q] = t2.x; f[2*q+1] = t2.y;
            }
        }
    } else {
        #pragma unroll
        for (int j = 0; j < 8; ++j) f[j] = (kbase + j < klim) ? p[j] : 0.f;
    }
    union { bf16x8 v; unsigned int u[4]; } r;
    #pragma unroll
    for (int q = 0; q < 4; ++q) {
        const float lo = nv ? f[2*q]   : 0.f;
        const float hi = nv ? f[2*q+1] : 0.f;
        const __hip_bfloat162 b2 = __float22bfloat162_rn(make_float2(lo, hi));
        unsigned int uu; __builtin_memcpy(&uu, &b2, 4);
        r.u[q] = uu;
    }
    return r.v;
}
__device__ __forceinline__ f32x4 MF(bf16x8 a, bf16x8 b, f32x4 c) {
    return __builtin_amdgcn_mfma_f32_16x16x32_bf16(a, b, c, 0, 0, 0);
}

// dense layer, direct W loads: wave w owns N-column w (16 cols), 2 M-tiles
#define DLAYER(INBUF, WPTR, KST, KLIM, BIAS, OUTBUF)                            \
    {                                                                           \
        const int nn = w * 16 + rl;                                             \
        const float bv = (nn < 100) ? (BIAS)[nn] : 0.f;                         \
        bf16x8 bfr[4];                                                          \
        _Pragma("unroll")                                                       \
        for (int ks = 0; ks < 4; ++ks)                                          \
            bfr[ks] = loadW(WPTR, KST, KLIM, 100, nn, ks * 32 + g8);            \
        _Pragma("unroll")                                                       \
        for (int m = 0; m < 2; ++m) {                                           \
            f32x4 acc; acc.x = bv; acc.y = bv; acc.z = bv; acc.w = bv;          \
            _Pragma("unroll")                                                   \
            for (int ks = 0; ks < 4; ++ks)                                      \
                acc = MF(ldA(INBUF, 128, m * 16 + rl, ks * 32 + g8), bfr[ks], acc); \
            _Pragma("unroll")                                                   \
            for (int r = 0; r < 4; ++r) {                                       \
                const int row = m * 16 + dr + r;                                \
                (OUTBUF)[((row << 7) + nn) ^ ((row & 7) << 3)] = f2bf(lrelu(acc[r])); \
            }                                                                   \
        }                                                                       \
    }

__global__ __launch_bounds__(TPB, 4)
void fused(const float* __restrict__ z_seq, const float* __restrict__ a_seq,
           const float* __restrict__ term_seq,
           const float* __restrict__ W1, const float* __restrict__ b1,
           const float* __restrict__ W2, const float* __restrict__ b2,
           const float* __restrict__ W3, const float* __restrict__ b3,
           const float* __restrict__ W4, const float* __restrict__ b4,
           const float* __restrict__ W5, const float* __restrict__ b5,
           const float* __restrict__ Wz, const float* __restrict__ bz,
           const float* __restrict__ Wt, const float* __restrict__ bt,
           float* __restrict__ ws, float* __restrict__ out)
{
    __shared__ unsigned short Vp[32 * 128];   // az -> inter (live through L5)
    __shared__ unsigned short Vq[32 * 128];   // v1 -> u -> i5
    __shared__ unsigned short Hb[32 * 64];    // h rows bf16
    __shared__ float Dl[32 * 64];             // delta f32
    __shared__ float csum_s[64];
    __shared__ float coff_s[64];
    __shared__ float redz[8];
    __shared__ unsigned int vid_s;

    const int tid  = threadIdx.x;
    const int lane = tid & 63;
    const int w    = __builtin_amdgcn_readfirstlane(tid >> 6);   // 0..7

    unsigned int* ticket = (unsigned int*)ws;
    unsigned int* done   = (unsigned int*)ws + 1;
    float* accz = ws + 2;
    float* acct = ws + 3;
    unsigned long long* st = (unsigned long long*)((char*)ws + WSB_ST);

    // logical chunk id via ticket (start-order => lookback is deadlock-free)
    if (tid == 0) vid_s = atomicAdd(ticket, 1u);
    // Hb pad cols 50..63 = 0 while waiting
    for (int i = tid; i < 224; i += TPB) {
        const int t = i / 7, p = i - t * 7;
        *(unsigned int*)&Hb[((t << 6) + 50 + 2 * p) ^ ((t & 7) << 3)] = 0u;
    }
    __syncthreads();
    const int vid = __builtin_amdgcn_readfirstlane((int)vid_s);
    const int t0  = vid * LPB;

    // ---- stage az rows bf16: cols 0,1=a; 2..101=z; 102..127=0 ----
    if (tid < 32) {
        const int t = tid;
        const float a0 = a_seq[(t0 + t) * 2 + 0];
        const float a1 = a_seq[(t0 + t) * 2 + 1];
        *(unsigned int*)&Vp[((t << 7) + 0) ^ ((t & 7) << 3)] =
            (unsigned int)f2bf(a0) | ((unsigned int)f2bf(a1) << 16);
    }
    for (int i = tid; i < 1600; i += TPB) {
        const int t = i / 50, p = i - t * 50;
        const float2 z2 = *(const float2*)(z_seq + (size_t)(t0 + t) * 100 + 2 * p);
        *(unsigned int*)&Vp[((t << 7) + 2 + 2 * p) ^ ((t & 7) << 3)] =
            (unsigned int)f2bf(z2.x) | ((unsigned int)f2bf(z2.y) << 16);
    }
    for (int i = tid; i < 416; i += TPB) {
        const int t = i / 13, p = i - t * 13;
        *(unsigned int*)&Vp[((t << 7) + 102 + 2 * p) ^ ((t & 7) << 3)] = 0u;
    }
    __syncthreads();

    const int rl = lane & 15;
    const int g8 = (lane >> 4) << 3;
    const int dr = (lane >> 4) << 2;

    // ---- L1..L3 ----
    DLAYER(Vp, W1, 102, 102, b1, Vq);     // az -> v1
    __syncthreads();
    DLAYER(Vq, W2, 100, 100, b2, Vp);     // v1 -> inter (stays in Vp)
    __syncthreads();
    DLAYER(Vp, W3, 100, 100, b3, Vq);     // inter -> u
    __syncthreads();

    // ---- L4: delta = W4 @ u + b4 (waves 0..3 -> Dl f32) ----
    if (w < 4) {
        const int nn = w * 16 + rl;
        const float bv = (nn < 50) ? b4[nn] : 0.f;
        bf16x8 bfr[4];
        #pragma unroll
        for (int ks = 0; ks < 4; ++ks)
            bfr[ks] = loadW(W4, 100, 100, 50, nn, ks * 32 + g8);
        #pragma unroll
        for (int m = 0; m < 2; ++m) {
            f32x4 acc; acc.x = bv; acc.y = bv; acc.z = bv; acc.w = bv;
            #pragma unroll
            for (int ks = 0; ks < 4; ++ks)
                acc = MF(ldA(Vq, 128, m * 16 + rl, ks * 32 + g8), bfr[ks], acc);
            #pragma unroll
            for (int r = 0; r < 4; ++r) {
                const int row = m * 16 + dr + r;
                Dl[row * 64 + (nn ^ row)] = acc[r];
            }
        }
    }
    __syncthreads();

    // ---- csum + EARLY aggregate publish (all data travels inside the atomic) ----
    for (int i = tid; i < 1600; i += TPB) {
        const int n = i >> 5, l = i & 31;
        float v = Dl[l * 64 + (n ^ l)];
        if (t0 + l >= NS) { v = 0.f; Dl[l * 64 + (n ^ l)] = 0.f; }
        float s = v;
        #pragma unroll
        for (int off = 16; off > 0; off >>= 1) s += __shfl_xor(s, off, 32);
        if ((lane & 31) == 0) {
            csum_s[n] = s;
            const unsigned long long pk =
                ((unsigned long long)(vid == 0 ? 2u : 1u) << 32) |
                (unsigned long long)__float_as_uint(s);
            __hip_atomic_store(&st[(size_t)vid * 64 + n], pk,
                               __ATOMIC_RELAXED, __HIP_MEMORY_SCOPE_AGENT);
        }
    }
    __syncthreads();

    // ---- decoupled lookback, window-64, dims n = w+8j pipelined per wave ----
    {
        float pref0=0.f,pref1=0.f,pref2=0.f,pref3=0.f,pref4=0.f,pref5=0.f,pref6=0.f;
        int   base0=vid-1,base1=vid-1,base2=vid-1,base3=vid-1,base4=vid-1,base5=vid-1,base6=vid-1;
        unsigned int alive = 0;
        #pragma unroll
        for (int j = 0; j < 7; ++j)
            if (w + 8 * j < 50 && vid > 0) alive |= (1u << j);

        #define LB_LOAD(J, BASE, SV)                                            \
            unsigned long long SV = 0ull;                                       \
            if (alive & (1u << J)) {                                            \
                const int p = (BASE) - lane;                                    \
                if (p >= 0)                                                     \
                    SV = __hip_atomic_load(&st[(size_t)p * 64 + (w + 8 * J)],   \
                             __ATOMIC_RELAXED, __HIP_MEMORY_SCOPE_AGENT);       \
            }
        #define LB_PROC(J, BASE, PREF, SV)                                      \
            if (alive & (1u << J)) {                                            \
                const int p = (BASE) - lane;                                    \
                const unsigned int tag = (unsigned int)(SV >> 32);              \
                const bool isIncl  = (p < 0) || (tag == 2u);                    \
                const bool isValid = (p < 0) || (tag != 0u);                    \
                if (!(~__ballot(isValid))) {                                    \
                    const unsigned long long im = __ballot(isIncl);             \
                    if (im) {                                                   \
                        const int fl = (int)__ffsll((long long)im) - 1;         \
                        float c = (lane <= fl && p >= 0)                        \
                                  ? __uint_as_float((unsigned int)SV) : 0.f;    \
                        _Pragma("unroll")                                       \
                        for (int o = 32; o > 0; o >>= 1) c += __shfl_xor(c, o, 64); \
                        PREF += c;                                              \
                        alive &= ~(1u << J);                                    \
                    } else {                                                    \
                        float c = __uint_as_float((unsigned int)SV);            \
                        _Pragma("unroll")                                       \
                        for (int o = 32; o > 0; o >>= 1) c += __shfl_xor(c, o, 64); \
                        PREF += c;                                              \
                        BASE -= 64;                                             \
                    }                                                           \
                }                                                               \
            }

        while (alive) {
            LB_LOAD(0, base0, sv0) LB_LOAD(1, base1, sv1) LB_LOAD(2, base2, sv2)
            LB_LOAD(3, base3, sv3) LB_LOAD(4, base4, sv4) LB_LOAD(5, base5, sv5)
            LB_LOAD(6, base6, sv6)
            LB_PROC(0, base0, pref0, sv0) LB_PROC(1, base1, pref1, sv1)
            LB_PROC(2, base2, pref2, sv2) LB_PROC(3, base3, pref3, sv3)
            LB_PROC(4, base4, pref4, sv4) LB_PROC(5, base5, pref5, sv5)
            LB_PROC(6, base6, pref6, sv6)
        }
        #undef LB_LOAD
        #undef LB_PROC

        if (lane == 0) {
            #define LB_FIN(J, PREF)                                             \
                {                                                               \
                    const int n = w + 8 * J;                                    \
                    if (n < 50) {                                               \
                        coff_s[n] = PREF;                                       \
                        if (vid > 0) {                                          \
                            const unsigned long long pk = (2ull << 32) |        \
                                (unsigned long long)__float_as_uint(PREF + csum_s[n]); \
                            __hip_atomic_store(&st[(size_t)vid * 64 + n], pk,   \
                                __ATOMIC_RELAXED, __HIP_MEMORY_SCOPE_AGENT);    \
                        } else coff_s[n] = 0.f;                                 \
                    }                                                           \
                }
            LB_FIN(0, pref0) LB_FIN(1, pref1) LB_FIN(2, pref2) LB_FIN(3, pref3)
            LB_FIN(4, pref4) LB_FIN(5, pref5) LB_FIN(6, pref6)
            #undef LB_FIN
        }
    }
    __syncthreads();

    // ---- 32-lane inclusive scan per dim + coff -> Hb ----
    for (int pass = 0; pass < 4; ++pass) {
        const int n = pass * 16 + w * 2 + (lane >> 5);
        if (n < 50) {
            const int sl = lane & 31;
            float v = Dl[sl * 64 + (n ^ sl)];
            #pragma unroll
            for (int off = 1; off < 32; off <<= 1) {
                const float u = __shfl_up(v, off, 32);
                if (sl >= off) v += u;
            }
            Hb[((sl << 6) + n) ^ ((sl & 7) << 3)] = f2bf(v + coff_s[n]);
        }
    }
    __syncthreads();

    // ---- L5: i5 = lrelu(W5 @ [h; inter] + b5) -> Vq ----
    {
        const int nn = w * 16 + rl;
        const float bv = (nn < 100) ? b5[nn] : 0.f;
        bf16x8 bfr[6];
        bfr[0] = loadW(W5, 150, 50, 100, nn, g8);
        bfr[1] = loadW(W5, 150, 50, 100, nn, 32 + g8);
        #pragma unroll
        for (int ks = 2; ks < 6; ++ks)
            bfr[ks] = loadW(W5, 150, 150, 100, nn, ks * 32 + g8 - 14);
        #pragma unroll
        for (int m = 0; m < 2; ++m) {
            f32x4 acc; acc.x = bv; acc.y = bv; acc.z = bv; acc.w = bv;
            #pragma unroll
            for (int ks = 0; ks < 6; ++ks) {
                const bf16x8 a = (ks < 2) ? ldA(Hb, 64, m * 16 + rl, ks * 32 + g8)
                                          : ldA(Vp, 128, m * 16 + rl, (ks - 2) * 32 + g8);
                acc = MF(a, bfr[ks], acc);
            }
            #pragma unroll
            for (int r = 0; r < 4; ++r) {
                const int row = m * 16 + dr + r;
                Vq[((row << 7) + nn) ^ ((row & 7) << 3)] = f2bf(lrelu(acc[r]));
            }
        }
    }
    __syncthreads();

    // ---- Lz: z_pred + squared error (z_next direct from global, f32) ----
    float zpart = 0.f;
    {
        const int nn = w * 16 + rl;
        const float bv = (nn < 100) ? bz[nn] : 0.f;
        bf16x8 bfr[4];
        #pragma unroll
        for (int ks = 0; ks < 4; ++ks)
            bfr[ks] = loadW(Wz, 100, 100, 100, nn, ks * 32 + g8);
        #pragma unroll
        for (int m = 0; m < 2; ++m) {
            f32x4 acc; acc.x = bv; acc.y = bv; acc.z = bv; acc.w = bv;
            #pragma unroll
            for (int ks = 0; ks < 4; ++ks)
                acc = MF(ldA(Vq, 128, m * 16 + rl, ks * 32 + g8), bfr[ks], acc);
            if (nn < 100) {
                #pragma unroll
                for (int r = 0; r < 4; ++r) {
                    const int row = m * 16 + dr + r;
                    if (t0 + row < NS) {
                        const float zn = z_seq[(size_t)(t0 + row + 1) * 100 + nn];
                        const float d = zn - acc[r];
                        zpart += d * d;
                    }
                }
            }
        }
    }

    // ---- Lt: t_logit + BCE (wave 0, lanes 0..31, lane = t) ----
    float tpart = 0.f;
    if (w == 0 && lane < 32) {
        const bool vl = (t0 + lane) < NS;
        float a = bt[0];
        #pragma unroll
        for (int g = 0; g < 13; ++g) {
            const bf16x8 v = *(const bf16x8*)(Vq + (((lane << 7) + 8 * g) ^ ((lane & 7) << 3)));
            #pragma unroll
            for (int j = 0; j < 8; ++j) {
                const int c = 8 * g + j;
                if (c < 100) a = fmaf(bf2f((unsigned short)v[j]), Wt[c], a);
            }
        }
        if (vl) {
            const float y = term_seq[t0 + lane + 1];
            tpart = fmaxf(a, 0.f) - a * y + log1pf(expf(-fabsf(a)));
        }
    }

    // ---- loss accumulation + done ticket; 512th block writes out ----
    #pragma unroll
    for (int off = 32; off > 0; off >>= 1) zpart += __shfl_xor(zpart, off, 64);
    if (lane == 0) redz[w] = zpart;
    if (w == 0) {
        #pragma unroll
        for (int off = 16; off > 0; off >>= 1) tpart += __shfl_xor(tpart, off, 32);
    }
    __syncthreads();
    if (tid == 0) {
        float s = 0.f;
        #pragma unroll
        for (int i = 0; i < 8; ++i) s += redz[i];
        atomicAdd(accz, s);
        atomicAdd(acct, tpart);
        const unsigned int old =
            __hip_atomic_fetch_add(done, 1u, __ATOMIC_ACQ_REL, __HIP_MEMORY_SCOPE_AGENT);
        if (old == (unsigned int)(NBLK - 1)) {
            const float sz  = __hip_atomic_load(accz, __ATOMIC_RELAXED, __HIP_MEMORY_SCOPE_AGENT);
            const float stt = __hip_atomic_load(acct, __ATOMIC_RELAXED, __HIP_MEMORY_SCOPE_AGENT);
            const float zl = sz / (100.0f * NS);
            const float tl = stt / NS;
            out[0] = zl + tl;
            out[1] = zl;
            out[2] = tl;
        }
    }
}

extern "C" void kernel_launch(void* const* d_in, const int* in_sizes, int n_in,
                              void* d_out, int out_size, void* d_ws, size_t ws_size,
                              hipStream_t stream)
{
    const float* z_seq = (const float*)d_in[0];
    const float* a_seq = (const float*)d_in[1];
    const float* term  = (const float*)d_in[2];
    const float* W1 = (const float*)d_in[3];  const float* b1 = (const float*)d_in[4];
    const float* W2 = (const float*)d_in[5];  const float* b2 = (const float*)d_in[6];
    const float* W3 = (const float*)d_in[7];  const float* b3 = (const float*)d_in[8];
    const float* W4 = (const float*)d_in[9];  const float* b4 = (const float*)d_in[10];
    const float* W5 = (const float*)d_in[11]; const float* b5 = (const float*)d_in[12];
    const float* Wz = (const float*)d_in[13]; const float* bz = (const float*)d_in[14];
    const float* Wt = (const float*)d_in[15]; const float* bt = (const float*)d_in[16];
    float* out = (float*)d_out;
    float* ws  = (float*)d_ws;

    hipMemsetAsync(ws, 0, WS_ZERO_BYTES, stream);
    fused<<<NBLK, TPB, 0, stream>>>(z_seq, a_seq, term,
                                    W1, b1, W2, b2, W3, b3, W4, b4,
                                    W5, b5, Wz, bz, Wt, bt, ws, out);
}

// Round 12
// 48.035 us; speedup vs baseline: 2.3188x; 2.3188x over previous
//
#include <hip/hip_runtime.h>
#include <hip/hip_bf16.h>
#include <math.h>

#define NS   16383
#define NSP  16384
#define LPB  32
#define NBLK 512
#define TPB  512
#define PACKBLK 80     // extra k1 blocks packing PK5/PKZ for k3

// ---- ws layout (float units) ----
#define OFF_INTR 0                          // interR [16384][64] uint rows (2xbf16)
#define OFF_DELT (OFF_INTR + 1048576)       // deltaT [50][NSP] f32
#define OFF_CSUM (OFF_DELT + 819200)        // 50*NBLK
#define OFF_CTRL (OFF_CSUM + 50*NBLK)       // [0]=done u32, [1]=accz f32, [2]=acct f32
#define OFF_PACK (OFF_CTRL + 4)             // 98304 ushort = 49152 floats

// ---- weight-pack offsets (ushort units) — only PK5/PKZ used ----
#define PK5 57344      // L5: NT=8 KS=6
#define PKZ 81920      // Lz: NT=8 KS=4
#define PKTOT 98304

using bf16x8 = __attribute__((ext_vector_type(8))) short;
using f32x4  = __attribute__((ext_vector_type(4))) float;

__device__ __forceinline__ unsigned short f2bf(float f) {
    unsigned int x = __float_as_uint(f);
    return (unsigned short)((x + 0x7fffu + ((x >> 16) & 1u)) >> 16);
}
__device__ __forceinline__ float bf2f(unsigned short u) {
    return __uint_as_float(((unsigned int)u) << 16);
}
__device__ __forceinline__ float lrelu(float x) { return fmaxf(x, 0.01f * x); }

// A-fragment from swizzled LDS rows: row-major, short-idx ^= (row&7)<<3
__device__ __forceinline__ bf16x8 ldA(const unsigned short* buf, int strideSh, int row, int kc) {
    const int idx = (row * strideSh + kc) ^ ((row & 7) << 3);
    return *(const bf16x8*)(buf + idx);
}
// B-fragment: pre-packed lane-linear in global (k3 path)
__device__ __forceinline__ bf16x8 ldB(const unsigned short* pk, int KS, int nt, int ks, int lane) {
    return *(const bf16x8*)(pk + (size_t)(((nt * KS + ks) << 6) + lane) * 8);
}
// B-fragment: DIRECT load from row-major W [Nmax][Kst], bf16-convert in regs (k1 path)
__device__ __forceinline__ bf16x8 loadW(const float* __restrict__ W, const int Kst,
                                        const int klim, const int Nmax,
                                        const int n, const int kbase) {
    const bool nv = (n < Nmax);
    const int nc = nv ? n : (Nmax - 1);
    const float* p = W + (size_t)nc * Kst + kbase;
    float f[8];
    if (kbase + 7 < klim) {
        if ((Kst & 3) == 0) {
            const float4 a = *(const float4*)p;
            const float4 b = *(const float4*)(p + 4);
            f[0]=a.x; f[1]=a.y; f[2]=a.z; f[3]=a.w;
            f[4]=b.x; f[5]=b.y; f[6]=b.z; f[7]=b.w;
        } else {
            #pragma unroll
            for (int q = 0; q < 4; ++q) {
                const float2 t2 = *(const float2*)(p + 2 * q);
                f[2*q] = t2.x; f[2*q+1] = t2.y;
            }
        }
    } else {
        #pragma unroll
        for (int j = 0; j < 8; ++j) f[j] = (kbase + j < klim) ? p[j] : 0.f;
    }
    union { bf16x8 v; unsigned int u[4]; } r;
    #pragma unroll
    for (int q = 0; q < 4; ++q) {
        const float lo = nv ? f[2*q]   : 0.f;
        const float hi = nv ? f[2*q+1] : 0.f;
        const __hip_bfloat162 b2 = __float22bfloat162_rn(make_float2(lo, hi));
        unsigned int uu; __builtin_memcpy(&uu, &b2, 4);
        r.u[q] = uu;
    }
    return r.v;
}
__device__ __forceinline__ f32x4 MF(bf16x8 a, bf16x8 b, f32x4 c) {
    return __builtin_amdgcn_mfma_f32_16x16x32_bf16(a, b, c, 0, 0, 0);
}

// dense layer with direct W loads: wave w owns N-column w, 2 M-tiles
#define DLAYER(INBUF, WPTR, KST, KLIM, BIAS, OUTBUF)                            \
    {                                                                           \
        const int nn = w * 16 + rl;                                             \
        const float bv = (nn < 100) ? (BIAS)[nn] : 0.f;                         \
        bf16x8 bfr[4];                                                          \
        _Pragma("unroll")                                                       \
        for (int ks = 0; ks < 4; ++ks)                                          \
            bfr[ks] = loadW(WPTR, KST, KLIM, 100, nn, ks * 32 + g8);            \
        _Pragma("unroll")                                                       \
        for (int m = 0; m < 2; ++m) {                                           \
            f32x4 acc; acc.x = bv; acc.y = bv; acc.z = bv; acc.w = bv;          \
            _Pragma("unroll")                                                   \
            for (int ks = 0; ks < 4; ++ks)                                      \
                acc = MF(ldA(INBUF, 128, m * 16 + rl, ks * 32 + g8), bfr[ks], acc); \
            _Pragma("unroll")                                                   \
            for (int r = 0; r < 4; ++r) {                                       \
                const int row = m * 16 + dr + r;                                \
                (OUTBUF)[((row << 7) + nn) ^ ((row & 7) << 3)] = f2bf(lrelu(acc[r])); \
            }                                                                   \
        }                                                                       \
    }

// ---------- k1: L1..L4 (blocks 0..511) + PK5/PKZ pack + ctrl zero (blocks 512..591) ----------
__global__ __launch_bounds__(TPB, 4)
void k1_encode(const float* __restrict__ z_seq, const float* __restrict__ a_seq,
               const float* __restrict__ W1, const float* __restrict__ b1,
               const float* __restrict__ W2, const float* __restrict__ b2,
               const float* __restrict__ W3, const float* __restrict__ b3,
               const float* __restrict__ W4, const float* __restrict__ b4,
               const float* __restrict__ W5, const float* __restrict__ Wz,
               float* __restrict__ ws)
{
    const int blk = blockIdx.x;
    const int tid = threadIdx.x;

    if (blk >= NBLK) {   // ---- pack PK5/PKZ fragments for k3; zero ctrl words ----
        if (blk == NBLK && tid == 0) {
            *(unsigned int*)(ws + OFF_CTRL) = 0u;   // done counter
            ws[OFF_CTRL + 1] = 0.f;                 // accz
            ws[OFF_CTRL + 2] = 0.f;                 // acct
        }
        const int idx = PK5 + (blk - NBLK) * TPB + tid;
        int e, KS, layer;
        if (idx < PKZ) { layer = 5; e = idx - PK5; KS = 6; }
        else           { layer = 6; e = idx - PKZ; KS = 4; }
        const int j    = e & 7;
        const int ln   = (e >> 3) & 63;
        const int rest = e >> 9;
        const int ks   = rest % KS;
        const int nt   = rest / KS;
        const int n    = nt * 16 + (ln & 15);
        const int k    = ks * 32 + ((ln >> 4) << 3) + j;
        float v = 0.f;
        if (layer == 5) { if (n < 100) {
                              if (k < 50) v = W5[n * 150 + k];
                              else if (k >= 64 && k < 164) v = W5[n * 150 + k - 14]; } }
        else            { if (n < 100 && k < 100) v = Wz[n * 100 + k]; }
        ((unsigned short*)(ws + OFF_PACK))[idx] = f2bf(v);
        return;
    }

    __shared__ unsigned short Vp[32 * 128];
    __shared__ unsigned short Vq[32 * 128];
    __shared__ float Dl[32 * 64];

    const int lane = tid & 63;
    const int w    = __builtin_amdgcn_readfirstlane(tid >> 6);
    const int t0   = blk * LPB;

    unsigned int* interR = (unsigned int*)(ws + OFF_INTR);
    float* deltaT = ws + OFF_DELT;
    float* csum   = ws + OFF_CSUM;

    // stage az rows bf16: cols 0,1=a; 2..101=z; 102..127=0
    if (tid < 32) {
        const int t = tid;
        const float a0 = a_seq[(t0 + t) * 2 + 0];
        const float a1 = a_seq[(t0 + t) * 2 + 1];
        *(unsigned int*)&Vp[((t << 7) + 0) ^ ((t & 7) << 3)] =
            (unsigned int)f2bf(a0) | ((unsigned int)f2bf(a1) << 16);
    }
    for (int i = tid; i < 1600; i += TPB) {
        const int t = i / 50, p = i - t * 50;
        const float2 z2 = *(const float2*)(z_seq + (size_t)(t0 + t) * 100 + 2 * p);
        *(unsigned int*)&Vp[((t << 7) + 2 + 2 * p) ^ ((t & 7) << 3)] =
            (unsigned int)f2bf(z2.x) | ((unsigned int)f2bf(z2.y) << 16);
    }
    for (int i = tid; i < 416; i += TPB) {
        const int t = i / 13, p = i - t * 13;
        *(unsigned int*)&Vp[((t << 7) + 102 + 2 * p) ^ ((t & 7) << 3)] = 0u;
    }
    __syncthreads();

    const int rl = lane & 15;
    const int g8 = (lane >> 4) << 3;
    const int dr = (lane >> 4) << 2;

    DLAYER(Vp, W1, 102, 102, b1, Vq);     // L1: az -> v1
    __syncthreads();
    DLAYER(Vq, W2, 100, 100, b2, Vp);     // L2: v1 -> inter
    __syncthreads();
    // inter -> global (uint rows, coalesced); L3 same phase (both read Vp)
    for (int i = tid; i < 2048; i += TPB) {
        const int t = i >> 6, c2 = i & 63;
        interR[(size_t)(t0 + t) * 64 + c2] =
            *(const unsigned int*)&Vp[((t << 7) + (c2 << 1)) ^ ((t & 7) << 3)];
    }
    DLAYER(Vp, W3, 100, 100, b3, Vq);     // L3: inter -> u
    __syncthreads();

    // L4: delta = W4 @ u + b4 (waves 0..3, f32 -> Dl)
    if (w < 4) {
        const int nn = w * 16 + rl;
        const float bv = (nn < 50) ? b4[nn] : 0.f;
        bf16x8 bfr[4];
        #pragma unroll
        for (int ks = 0; ks < 4; ++ks)
            bfr[ks] = loadW(W4, 100, 100, 50, nn, ks * 32 + g8);
        #pragma unroll
        for (int m = 0; m < 2; ++m) {
            f32x4 acc; acc.x = bv; acc.y = bv; acc.z = bv; acc.w = bv;
            #pragma unroll
            for (int ks = 0; ks < 4; ++ks)
                acc = MF(ldA(Vq, 128, m * 16 + rl, ks * 32 + g8), bfr[ks], acc);
            #pragma unroll
            for (int r = 0; r < 4; ++r) {
                const int row = m * 16 + dr + r;
                Dl[row * 64 + (nn ^ row)] = acc[r];
            }
        }
    }
    __syncthreads();

    // delta -> global [n][t] + per-chunk sums (32-lane groups)
    for (int i = tid; i < 1600; i += TPB) {
        const int n = i >> 5, l = i & 31;
        float v = Dl[l * 64 + (n ^ l)];
        if (t0 + l >= NS) v = 0.f;
        deltaT[n * NSP + t0 + l] = v;
        float s = v;
        #pragma unroll
        for (int off = 16; off > 0; off >>= 1) s += __shfl_xor(s, off, 32);
        if ((lane & 31) == 0) csum[n * NBLK + blk] = s;
    }
}

// ---------- k3: coff + h-scan + L5/Lz/Lt + atomic loss finish ----------
__global__ __launch_bounds__(TPB, 4)
void k3_predict(const float* __restrict__ z_seq, const float* __restrict__ term_seq,
                const float* __restrict__ b5, const float* __restrict__ bz,
                const float* __restrict__ Wt, const float* __restrict__ bt,
                float* __restrict__ ws, float* __restrict__ out)
{
    __shared__ unsigned short Ib[32 * 128];   // inter rows
    __shared__ unsigned short I5[32 * 128];   // i5 rows
    __shared__ unsigned short Hb[32 * 64];    // h rows
    __shared__ float Dl[32 * 64];             // delta
    __shared__ float redz[8];
    __shared__ float redt;

    const int tid  = threadIdx.x;
    const int lane = tid & 63;
    const int w    = __builtin_amdgcn_readfirstlane(tid >> 6);
    const int blk  = blockIdx.x;
    const int t0   = blk * LPB;

    const unsigned short* packw = (const unsigned short*)(ws + OFF_PACK);
    const unsigned int* interR = (const unsigned int*)(ws + OFF_INTR);
    const float* deltaT = ws + OFF_DELT;
    const float* csum   = ws + OFF_CSUM;

    for (int i = tid; i < 2048; i += TPB) {
        const int t = i >> 6, c2 = i & 63;
        *(unsigned int*)&Ib[((t << 7) + (c2 << 1)) ^ ((t & 7) << 3)] =
            interR[(size_t)(t0 + t) * 64 + c2];
    }
    for (int i = tid; i < 1600; i += TPB) {
        const int n = i >> 5, l = i & 31;
        Dl[l * 64 + (n ^ l)] = deltaT[n * NSP + t0 + l];
    }
    for (int i = tid; i < 224; i += TPB) {   // Hb pad cols 50..63
        const int t = i / 7, p = i - t * 7;
        *(unsigned int*)&Hb[((t << 6) + 50 + 2 * p) ^ ((t & 7) << 3)] = 0u;
    }
    __syncthreads();

    // coff (float4-vectorized chunk-sum read) + inclusive 32-lane scan
    for (int pass = 0; pass < 4; ++pass) {
        const int n = pass * 16 + w * 2 + (lane >> 5);
        if (n < 50) {
            const int sl = lane & 31;
            float s = 0.f;
            #pragma unroll
            for (int i2 = 0; i2 < 4; ++i2) {
                const int c0 = (sl + (i2 << 5)) << 2;
                if (c0 < blk) {
                    const f32x4 v4 = *(const f32x4*)(csum + n * NBLK + c0);
                    #pragma unroll
                    for (int e = 0; e < 4; ++e)
                        if (c0 + e < blk) s += v4[e];
                }
            }
            #pragma unroll
            for (int off = 16; off > 0; off >>= 1) s += __shfl_xor(s, off, 32);
            float v = Dl[sl * 64 + (n ^ sl)];
            #pragma unroll
            for (int off = 1; off < 32; off <<= 1) {
                const float u = __shfl_up(v, off, 32);
                if (sl >= off) v += u;
            }
            Hb[((sl << 6) + n) ^ ((sl & 7) << 3)] = f2bf(v + s);
        }
    }
    __syncthreads();

    const int rl = lane & 15;
    const int g8 = (lane >> 4) << 3;
    const int dr = (lane >> 4) << 2;

    // L5: i5 = lrelu(W5 @ [h(K0..63); inter(K64..191)] + b5) -> I5
    {
        const int nn = w * 16 + rl;
        const float bv = (nn < 100) ? b5[nn] : 0.f;
        bf16x8 bfr[6];
        #pragma unroll
        for (int ks = 0; ks < 6; ++ks) bfr[ks] = ldB(packw + PK5, 6, w, ks, lane);
        #pragma unroll
        for (int m = 0; m < 2; ++m) {
            f32x4 acc; acc.x = bv; acc.y = bv; acc.z = bv; acc.w = bv;
            #pragma unroll
            for (int ks = 0; ks < 6; ++ks) {
                const bf16x8 a = (ks < 2) ? ldA(Hb, 64, m * 16 + rl, ks * 32 + g8)
                                          : ldA(Ib, 128, m * 16 + rl, (ks - 2) * 32 + g8);
                acc = MF(a, bfr[ks], acc);
            }
            #pragma unroll
            for (int r = 0; r < 4; ++r) {
                const int row = m * 16 + dr + r;
                I5[((row << 7) + nn) ^ ((row & 7) << 3)] = f2bf(lrelu(acc[r]));
            }
        }
    }
    __syncthreads();

    // Lz: z_pred + squared error vs z_next read DIRECTLY from global (f32)
    float zpart = 0.f;
    {
        const int nn = w * 16 + rl;
        const float bv = (nn < 100) ? bz[nn] : 0.f;
        bf16x8 bfr[4];
        #pragma unroll
        for (int ks = 0; ks < 4; ++ks) bfr[ks] = ldB(packw + PKZ, 4, w, ks, lane);
        #pragma unroll
        for (int m = 0; m < 2; ++m) {
            f32x4 acc; acc.x = bv; acc.y = bv; acc.z = bv; acc.w = bv;
            #pragma unroll
            for (int ks = 0; ks < 4; ++ks)
                acc = MF(ldA(I5, 128, m * 16 + rl, ks * 32 + g8), bfr[ks], acc);
            if (nn < 100) {
                #pragma unroll
                for (int r = 0; r < 4; ++r) {
                    const int row = m * 16 + dr + r;
                    if (t0 + row < NS) {
                        const float zn = z_seq[(size_t)(t0 + row + 1) * 100 + nn];
                        const float d = zn - acc[r];
                        zpart += d * d;
                    }
                }
            }
        }
    }

    // Lt: t_logit + BCE (wave 0, lanes 0..31, lane = t)
    float tpart = 0.f;
    if (w == 0 && lane < 32) {
        const bool vl = (t0 + lane) < NS;
        float a = bt[0];
        #pragma unroll
        for (int g = 0; g < 13; ++g) {
            const bf16x8 v = *(const bf16x8*)(I5 + (((lane << 7) + 8 * g) ^ ((lane & 7) << 3)));
            #pragma unroll
            for (int j = 0; j < 8; ++j) {
                const int c = 8 * g + j;
                if (c < 100) a = fmaf(bf2f((unsigned short)v[j]), Wt[c], a);
            }
        }
        if (vl) {
            const float y = term_seq[t0 + lane + 1];
            tpart = fmaxf(a, 0.f) - a * y + log1pf(expf(-fabsf(a)));
        }
    }

    // ---- per-block reduce + fence-free atomic finish ----
    #pragma unroll
    for (int off = 32; off > 0; off >>= 1) zpart += __shfl_xor(zpart, off, 64);
    if (lane == 0) redz[w] = zpart;
    if (w == 0) {
        #pragma unroll
        for (int off = 16; off > 0; off >>= 1) tpart += __shfl_xor(tpart, off, 32);
        if (lane == 0) redt = tpart;
    }
    __syncthreads();
    if (tid == 0) {
        float s = 0.f;
        #pragma unroll
        for (int i = 0; i < 8; ++i) s += redz[i];
        float* accz = ws + OFF_CTRL + 1;
        float* acct = ws + OFF_CTRL + 2;
        unsigned int* done = (unsigned int*)(ws + OFF_CTRL);
        // data travels inside the atomics; consuming the returns forces the RMWs
        // to be globally performed before the done-increment issues. NO fences.
        const float oz = atomicAdd(accz, s);
        const float ot = atomicAdd(acct, redt);
        asm volatile("" :: "v"(oz), "v"(ot) : "memory");
        const unsigned int old = atomicAdd(done, 1u);
        if (old == (unsigned int)(NBLK - 1)) {
            const float sz  = __hip_atomic_load(accz, __ATOMIC_RELAXED, __HIP_MEMORY_SCOPE_AGENT);
            const float stt = __hip_atomic_load(acct, __ATOMIC_RELAXED, __HIP_MEMORY_SCOPE_AGENT);
            const float zl = sz / (100.0f * NS);
            const float tl = stt / NS;
            out[0] = zl + tl;
            out[1] = zl;
            out[2] = tl;
        }
    }
}

extern "C" void kernel_launch(void* const* d_in, const int* in_sizes, int n_in,
                              void* d_out, int out_size, void* d_ws, size_t ws_size,
                              hipStream_t stream)
{
    const float* z_seq = (const float*)d_in[0];
    const float* a_seq = (const float*)d_in[1];
    const float* term  = (const float*)d_in[2];
    const float* W1 = (const float*)d_in[3];  const float* b1 = (const float*)d_in[4];
    const float* W2 = (const float*)d_in[5];  const float* b2 = (const float*)d_in[6];
    const float* W3 = (const float*)d_in[7];  const float* b3 = (const float*)d_in[8];
    const float* W4 = (const float*)d_in[9];  const float* b4 = (const float*)d_in[10];
    const float* W5 = (const float*)d_in[11]; const float* b5 = (const float*)d_in[12];
    const float* Wz = (const float*)d_in[13]; const float* bz = (const float*)d_in[14];
    const float* Wt = (const float*)d_in[15]; const float* bt = (const float*)d_in[16];
    float* out = (float*)d_out;
    float* ws  = (float*)d_ws;

    k1_encode<<<NBLK + PACKBLK, TPB, 0, stream>>>(z_seq, a_seq, W1, b1, W2, b2,
                                                  W3, b3, W4, b4, W5, Wz, ws);
    k3_predict<<<NBLK, TPB, 0, stream>>>(z_seq, term, b5, bz, Wt, bt, ws, out);
}

// Round 13
// 31.380 us; speedup vs baseline: 3.5494x; 1.5307x over previous
//
#include <hip/hip_runtime.h>
#include <math.h>

#define NS   16383
#define NSP  16384
#define LPB  32
#define NBLK 512
#define TPB  512

// ---- ws layout (float units) ----
#define OFF_INTR 0                          // interR [16384][64] uint rows (2xbf16)
#define OFF_DELT (OFF_INTR + 1048576)       // deltaT [50][NSP] f32
#define OFF_CSUM (OFF_DELT + 819200)        // 50*NBLK
#define OFF_BZ   (OFF_CSUM + 50*NBLK)       // NBLK
#define OFF_BT   (OFF_BZ + NBLK)            // NBLK
#define OFF_PACK (OFF_BT + NBLK)            // 98304 ushort = 49152 floats

// ---- weight-pack offsets (ushort units) ----
#define PK1 0          // L1: NT=8 KS=4
#define PK2 16384      // L2: NT=8 KS=4
#define PK3 32768      // L3: NT=8 KS=4
#define PK4 49152      // L4: NT=4 KS=4
#define PK5 57344      // L5: NT=8 KS=6
#define PKZ 81920      // Lz: NT=8 KS=4
#define PKTOT 98304

using bf16x8 = __attribute__((ext_vector_type(8))) short;
using f32x4  = __attribute__((ext_vector_type(4))) float;

__device__ __forceinline__ unsigned short f2bf(float f) {
    unsigned int x = __float_as_uint(f);
    return (unsigned short)((x + 0x7fffu + ((x >> 16) & 1u)) >> 16);
}
__device__ __forceinline__ float bf2f(unsigned short u) {
    return __uint_as_float(((unsigned int)u) << 16);
}
__device__ __forceinline__ float lrelu(float x) { return fmaxf(x, 0.01f * x); }

// A-fragment from swizzled LDS rows: row-major, short-idx ^= (row&7)<<3
__device__ __forceinline__ bf16x8 ldA(const unsigned short* buf, int strideSh, int row, int kc) {
    const int idx = (row * strideSh + kc) ^ ((row & 7) << 3);
    return *(const bf16x8*)(buf + idx);
}
// B-fragment: pre-packed lane-linear in global (coalesced dwordx4, L2/L3-resident)
__device__ __forceinline__ bf16x8 ldB(const unsigned short* pk, int KS, int nt, int ks, int lane) {
    return *(const bf16x8*)(pk + (size_t)(((nt * KS + ks) << 6) + lane) * 8);
}
__device__ __forceinline__ f32x4 MF(bf16x8 a, bf16x8 b, f32x4 c) {
    return __builtin_amdgcn_mfma_f32_16x16x32_bf16(a, b, c, 0, 0, 0);
}

// one dense layer: wave w owns N-tile column w (16 cols), loops 2 M-tiles (32 rows)
#define MLAYER(INBUF, PKOFF, KSN, BIAS, OUTBUF)                                 \
    {                                                                           \
        const int nn = w * 16 + rl;                                             \
        const float bv = (nn < 100) ? (BIAS)[nn] : 0.f;                         \
        bf16x8 bfr[KSN];                                                        \
        _Pragma("unroll")                                                       \
        for (int ks = 0; ks < (KSN); ++ks)                                      \
            bfr[ks] = ldB(packw + (PKOFF), KSN, w, ks, lane);                   \
        _Pragma("unroll")                                                       \
        for (int m = 0; m < 2; ++m) {                                           \
            f32x4 acc; acc.x = bv; acc.y = bv; acc.z = bv; acc.w = bv;          \
            _Pragma("unroll")                                                   \
            for (int ks = 0; ks < (KSN); ++ks)                                  \
                acc = MF(ldA(INBUF, 128, m * 16 + rl, ks * 32 + g8), bfr[ks], acc); \
            _Pragma("unroll")                                                   \
            for (int r = 0; r < 4; ++r) {                                       \
                const int row = m * 16 + dr + r;                                \
                (OUTBUF)[((row << 7) + nn) ^ ((row & 7) << 3)] = f2bf(lrelu(acc[r])); \
            }                                                                   \
        }                                                                       \
    }

// ---------- k0: pack weights ----------
__global__ __launch_bounds__(256)
void k0_pack(const float* __restrict__ W1, const float* __restrict__ W2,
             const float* __restrict__ W3, const float* __restrict__ W4,
             const float* __restrict__ W5, const float* __restrict__ Wz,
             float* __restrict__ ws)
{
    const int idx = blockIdx.x * 256 + threadIdx.x;
    if (idx >= PKTOT) return;
    int e, KS, layer;
    if      (idx < PK2) { layer = 1; e = idx - PK1; KS = 4; }
    else if (idx < PK3) { layer = 2; e = idx - PK2; KS = 4; }
    else if (idx < PK4) { layer = 3; e = idx - PK3; KS = 4; }
    else if (idx < PK5) { layer = 4; e = idx - PK4; KS = 4; }
    else if (idx < PKZ) { layer = 5; e = idx - PK5; KS = 6; }
    else                { layer = 6; e = idx - PKZ; KS = 4; }
    const int j    = e & 7;
    const int ln   = (e >> 3) & 63;
    const int rest = e >> 9;
    const int ks   = rest % KS;
    const int nt   = rest / KS;
    const int n    = nt * 16 + (ln & 15);
    const int k    = ks * 32 + ((ln >> 4) << 3) + j;
    float v = 0.f;
    if (layer == 1)      { if (n < 100 && k < 102) v = W1[n * 102 + k]; }
    else if (layer == 2) { if (n < 100 && k < 100) v = W2[n * 100 + k]; }
    else if (layer == 3) { if (n < 100 && k < 100) v = W3[n * 100 + k]; }
    else if (layer == 4) { if (n < 50  && k < 100) v = W4[n * 100 + k]; }
    else if (layer == 5) { if (n < 100) {
                               if (k < 50) v = W5[n * 150 + k];
                               else if (k >= 64 && k < 164) v = W5[n * 150 + k - 14]; } }
    else                 { if (n < 100 && k < 100) v = Wz[n * 100 + k]; }
    ((unsigned short*)(ws + OFF_PACK))[idx] = f2bf(v);
}

// ---------- k1: L1..L4, 32 timesteps/block ----------
__global__ __launch_bounds__(TPB, 4)
void k1_encode(const float* __restrict__ z_seq, const float* __restrict__ a_seq,
               const float* __restrict__ b1, const float* __restrict__ b2,
               const float* __restrict__ b3, const float* __restrict__ b4,
               float* __restrict__ ws)
{
    __shared__ unsigned short Vp[32 * 128];
    __shared__ unsigned short Vq[32 * 128];
    __shared__ float Dl[32 * 64];

    const int tid  = threadIdx.x;
    const int lane = tid & 63;
    const int w    = __builtin_amdgcn_readfirstlane(tid >> 6);
    const int blk  = blockIdx.x;
    const int t0   = blk * LPB;

    const unsigned short* packw = (const unsigned short*)(ws + OFF_PACK);
    unsigned int* interR = (unsigned int*)(ws + OFF_INTR);
    float* deltaT = ws + OFF_DELT;
    float* csum   = ws + OFF_CSUM;

    // stage az rows bf16: cols 0,1=a; 2..101=z; 102..127=0
    if (tid < 32) {
        const int t = tid;
        const float a0 = a_seq[(t0 + t) * 2 + 0];
        const float a1 = a_seq[(t0 + t) * 2 + 1];
        *(unsigned int*)&Vp[((t << 7) + 0) ^ ((t & 7) << 3)] =
            (unsigned int)f2bf(a0) | ((unsigned int)f2bf(a1) << 16);
    }
    for (int i = tid; i < 1600; i += TPB) {
        const int t = i / 50, p = i - t * 50;
        const float2 z2 = *(const float2*)(z_seq + (size_t)(t0 + t) * 100 + 2 * p);
        *(unsigned int*)&Vp[((t << 7) + 2 + 2 * p) ^ ((t & 7) << 3)] =
            (unsigned int)f2bf(z2.x) | ((unsigned int)f2bf(z2.y) << 16);
    }
    for (int i = tid; i < 416; i += TPB) {
        const int t = i / 13, p = i - t * 13;
        *(unsigned int*)&Vp[((t << 7) + 102 + 2 * p) ^ ((t & 7) << 3)] = 0u;
    }
    __syncthreads();

    const int rl = lane & 15;
    const int g8 = (lane >> 4) << 3;
    const int dr = (lane >> 4) << 2;

    MLAYER(Vp, PK1, 4, b1, Vq);     // L1: az -> v1
    __syncthreads();
    MLAYER(Vq, PK2, 4, b2, Vp);     // L2: v1 -> inter
    __syncthreads();
    // inter -> global (uint rows, coalesced); L3 same phase (both read Vp)
    for (int i = tid; i < 2048; i += TPB) {
        const int t = i >> 6, c2 = i & 63;
        interR[(size_t)(t0 + t) * 64 + c2] =
            *(const unsigned int*)&Vp[((t << 7) + (c2 << 1)) ^ ((t & 7) << 3)];
    }
    MLAYER(Vp, PK3, 4, b3, Vq);     // L3: inter -> u
    __syncthreads();

    // L4: delta = W4 @ u + b4 (waves 0..3, f32 -> Dl)
    if (w < 4) {
        const int nn = w * 16 + rl;
        const float bv = (nn < 50) ? b4[nn] : 0.f;
        bf16x8 bfr[4];
        #pragma unroll
        for (int ks = 0; ks < 4; ++ks) bfr[ks] = ldB(packw + PK4, 4, w, ks, lane);
        #pragma unroll
        for (int m = 0; m < 2; ++m) {
            f32x4 acc; acc.x = bv; acc.y = bv; acc.z = bv; acc.w = bv;
            #pragma unroll
            for (int ks = 0; ks < 4; ++ks)
                acc = MF(ldA(Vq, 128, m * 16 + rl, ks * 32 + g8), bfr[ks], acc);
            #pragma unroll
            for (int r = 0; r < 4; ++r) {
                const int row = m * 16 + dr + r;
                Dl[row * 64 + (nn ^ row)] = acc[r];
            }
        }
    }
    __syncthreads();

    // delta -> global [n][t] + per-chunk sums (32-lane groups)
    for (int i = tid; i < 1600; i += TPB) {
        const int n = i >> 5, l = i & 31;
        float v = Dl[l * 64 + (n ^ l)];
        if (t0 + l >= NS) v = 0.f;
        deltaT[n * NSP + t0 + l] = v;
        float s = v;
        #pragma unroll
        for (int off = 16; off > 0; off >>= 1) s += __shfl_xor(s, off, 32);
        if ((lane & 31) == 0) csum[n * NBLK + blk] = s;
    }
}

// ---------- k3: coff + h-scan + L5/Lz/Lt + per-block losses ----------
__global__ __launch_bounds__(TPB, 4)
void k3_predict(const float* __restrict__ z_seq, const float* __restrict__ term_seq,
                const float* __restrict__ b5, const float* __restrict__ bz,
                const float* __restrict__ Wt, const float* __restrict__ bt,
                float* __restrict__ ws)
{
    __shared__ unsigned short Ib[32 * 128];   // inter rows
    __shared__ unsigned short I5[32 * 128];   // i5 rows
    __shared__ unsigned short Hb[32 * 64];    // h rows
    __shared__ float Dl[32 * 64];             // delta
    __shared__ float redz[8];

    const int tid  = threadIdx.x;
    const int lane = tid & 63;
    const int w    = __builtin_amdgcn_readfirstlane(tid >> 6);
    const int blk  = blockIdx.x;
    const int t0   = blk * LPB;

    const unsigned short* packw = (const unsigned short*)(ws + OFF_PACK);
    const unsigned int* interR = (const unsigned int*)(ws + OFF_INTR);
    const float* deltaT = ws + OFF_DELT;
    const float* csum   = ws + OFF_CSUM;
    float* g_bz = ws + OFF_BZ;
    float* g_bt = ws + OFF_BT;

    for (int i = tid; i < 2048; i += TPB) {
        const int t = i >> 6, c2 = i & 63;
        *(unsigned int*)&Ib[((t << 7) + (c2 << 1)) ^ ((t & 7) << 3)] =
            interR[(size_t)(t0 + t) * 64 + c2];
    }
    for (int i = tid; i < 1600; i += TPB) {
        const int n = i >> 5, l = i & 31;
        Dl[l * 64 + (n ^ l)] = deltaT[n * NSP + t0 + l];
    }
    for (int i = tid; i < 224; i += TPB) {   // Hb pad cols 50..63
        const int t = i / 7, p = i - t * 7;
        *(unsigned int*)&Hb[((t << 6) + 50 + 2 * p) ^ ((t & 7) << 3)] = 0u;
    }
    __syncthreads();

    // coff (float4-vectorized chunk-sum read) + inclusive 32-lane scan
    for (int pass = 0; pass < 4; ++pass) {
        const int n = pass * 16 + w * 2 + (lane >> 5);
        if (n < 50) {
            const int sl = lane & 31;
            float s = 0.f;
            #pragma unroll
            for (int i2 = 0; i2 < 4; ++i2) {
                const int c0 = (sl + (i2 << 5)) << 2;
                if (c0 < blk) {
                    const f32x4 v4 = *(const f32x4*)(csum + n * NBLK + c0);
                    #pragma unroll
                    for (int e = 0; e < 4; ++e)
                        if (c0 + e < blk) s += v4[e];
                }
            }
            #pragma unroll
            for (int off = 16; off > 0; off >>= 1) s += __shfl_xor(s, off, 32);
            float v = Dl[sl * 64 + (n ^ sl)];
            #pragma unroll
            for (int off = 1; off < 32; off <<= 1) {
                const float u = __shfl_up(v, off, 32);
                if (sl >= off) v += u;
            }
            Hb[((sl << 6) + n) ^ ((sl & 7) << 3)] = f2bf(v + s);
        }
    }
    __syncthreads();

    const int rl = lane & 15;
    const int g8 = (lane >> 4) << 3;
    const int dr = (lane >> 4) << 2;

    // L5: i5 = lrelu(W5 @ [h(K0..63); inter(K64..191)] + b5) -> I5
    {
        const int nn = w * 16 + rl;
        const float bv = (nn < 100) ? b5[nn] : 0.f;
        bf16x8 bfr[6];
        #pragma unroll
        for (int ks = 0; ks < 6; ++ks) bfr[ks] = ldB(packw + PK5, 6, w, ks, lane);
        #pragma unroll
        for (int m = 0; m < 2; ++m) {
            f32x4 acc; acc.x = bv; acc.y = bv; acc.z = bv; acc.w = bv;
            #pragma unroll
            for (int ks = 0; ks < 6; ++ks) {
                const bf16x8 a = (ks < 2) ? ldA(Hb, 64, m * 16 + rl, ks * 32 + g8)
                                          : ldA(Ib, 128, m * 16 + rl, (ks - 2) * 32 + g8);
                acc = MF(a, bfr[ks], acc);
            }
            #pragma unroll
            for (int r = 0; r < 4; ++r) {
                const int row = m * 16 + dr + r;
                I5[((row << 7) + nn) ^ ((row & 7) << 3)] = f2bf(lrelu(acc[r]));
            }
        }
    }
    __syncthreads();

    // Lz: z_pred + squared error vs z_next read DIRECTLY from global (f32)
    float zpart = 0.f;
    {
        const int nn = w * 16 + rl;
        const float bv = (nn < 100) ? bz[nn] : 0.f;
        bf16x8 bfr[4];
        #pragma unroll
        for (int ks = 0; ks < 4; ++ks) bfr[ks] = ldB(packw + PKZ, 4, w, ks, lane);
        #pragma unroll
        for (int m = 0; m < 2; ++m) {
            f32x4 acc; acc.x = bv; acc.y = bv; acc.z = bv; acc.w = bv;
            #pragma unroll
            for (int ks = 0; ks < 4; ++ks)
                acc = MF(ldA(I5, 128, m * 16 + rl, ks * 32 + g8), bfr[ks], acc);
            if (nn < 100) {
                #pragma unroll
                for (int r = 0; r < 4; ++r) {
                    const int row = m * 16 + dr + r;
                    if (t0 + row < NS) {
                        const float zn = z_seq[(size_t)(t0 + row + 1) * 100 + nn];
                        const float d = zn - acc[r];
                        zpart += d * d;
                    }
                }
            }
        }
    }

    // Lt: t_logit + BCE (wave 0, lanes 0..31, lane = t)
    float tpart = 0.f;
    if (w == 0 && lane < 32) {
        const bool vl = (t0 + lane) < NS;
        float a = bt[0];
        #pragma unroll
        for (int g = 0; g < 13; ++g) {
            const bf16x8 v = *(const bf16x8*)(I5 + (((lane << 7) + 8 * g) ^ ((lane & 7) << 3)));
            #pragma unroll
            for (int j = 0; j < 8; ++j) {
                const int c = 8 * g + j;
                if (c < 100) a = fmaf(bf2f((unsigned short)v[j]), Wt[c], a);
            }
        }
        if (vl) {
            const float y = term_seq[t0 + lane + 1];
            tpart = fmaxf(a, 0.f) - a * y + log1pf(expf(-fabsf(a)));
        }
    }

    #pragma unroll
    for (int off = 32; off > 0; off >>= 1) zpart += __shfl_xor(zpart, off, 64);
    if (lane == 0) redz[w] = zpart;
    __syncthreads();
    if (tid == 0) {
        float s = 0.f;
        #pragma unroll
        for (int i = 0; i < 8; ++i) s += redz[i];
        g_bz[blk] = s;
    }
    if (w == 0) {
        #pragma unroll
        for (int off = 16; off > 0; off >>= 1) tpart += __shfl_xor(tpart, off, 32);
        if (lane == 0) g_bt[blk] = tpart;
    }
}

// ---------- k4: final reduce (512 partials) ----------
__global__ __launch_bounds__(512)
void k4_final(const float* __restrict__ ws, float* __restrict__ out)
{
    __shared__ float rz[8], rt[8];
    const float* g_bz = ws + OFF_BZ;
    const float* g_bt = ws + OFF_BT;
    const int tid  = threadIdx.x;
    const int lane = tid & 63;
    const int w    = tid >> 6;
    float z = g_bz[tid];
    float t = g_bt[tid];
    #pragma unroll
    for (int off = 32; off > 0; off >>= 1) {
        z += __shfl_xor(z, off, 64);
        t += __shfl_xor(t, off, 64);
    }
    if (lane == 0) { rz[w] = z; rt[w] = t; }
    __syncthreads();
    if (tid == 0) {
        float sz = 0.f, st = 0.f;
        #pragma unroll
        for (int i = 0; i < 8; ++i) { sz += rz[i]; st += rt[i]; }
        const float zl = sz / (100.0f * NS);
        const float tl = st / NS;
        out[0] = zl + tl;
        out[1] = zl;
        out[2] = tl;
    }
}

extern "C" void kernel_launch(void* const* d_in, const int* in_sizes, int n_in,
                              void* d_out, int out_size, void* d_ws, size_t ws_size,
                              hipStream_t stream)
{
    const float* z_seq = (const float*)d_in[0];
    const float* a_seq = (const float*)d_in[1];
    const float* term  = (const float*)d_in[2];
    const float* W1 = (const float*)d_in[3];  const float* b1 = (const float*)d_in[4];
    const float* W2 = (const float*)d_in[5];  const float* b2 = (const float*)d_in[6];
    const float* W3 = (const float*)d_in[7];  const float* b3 = (const float*)d_in[8];
    const float* W4 = (const float*)d_in[9];  const float* b4 = (const float*)d_in[10];
    const float* W5 = (const float*)d_in[11]; const float* b5 = (const float*)d_in[12];
    const float* Wz = (const float*)d_in[13]; const float* bz = (const float*)d_in[14];
    const float* Wt = (const float*)d_in[15]; const float* bt = (const float*)d_in[16];
    float* out = (float*)d_out;
    float* ws  = (float*)d_ws;

    k0_pack<<<384, 256, 0, stream>>>(W1, W2, W3, W4, W5, Wz, ws);
    k1_encode<<<NBLK, TPB, 0, stream>>>(z_seq, a_seq, b1, b2, b3, b4, ws);
    k3_predict<<<NBLK, TPB, 0, stream>>>(z_seq, term, b5, bz, Wt, bt, ws);
    k4_final<<<1, 512, 0, stream>>>(ws, out);
}